// Round 18
// baseline (61.465 us; speedup 1.0000x reference)
//
#include <hip/hip_runtime.h>
#include <hip/hip_fp16.h>

// r17 base (59.7 us, first spill-free build: WRITE 135 MB, VGPR 52) + 3 fixes:
//  (a) cgrp slab stride 1536 -> 1540 floats: r17's cgrp-pairs read the same
//      quad index in slabs 6144 B apart (0 mod 32 banks) -> every stencil b128
//      2-wide bank-aliased (conflicts 3.67M -> 6.03M). +4 pad de-aliases.
//  (b) double-buffered phase-1 slabs, ONE barrier per chunk (write next into
//      other buffer, read current, single sync): 16 -> 9 barriers.
//  (c) double-buffered phase-3 T tile, one barrier per cb: 8 -> 4 barriers.
// Structure otherwise r17-verified: 512 thr, 4 lanes/pos (chalf, cgrp), 8
// chunks/cgroup, f16 keep, shfl_xor(1)+(2) reduce, stride-36 exchange tile.

#define SLAB_CG 1540
#define SLAB_BUF 3080
#define T_STRIDE 4608

__device__ __forceinline__ float dot4acc(float4 a, float4 b, float acc) {
    acc = fmaf(a.x, b.x, acc);
    acc = fmaf(a.y, b.y, acc);
    acc = fmaf(a.z, b.z, acc);
    acc = fmaf(a.w, b.w, acc);
    return acc;
}

__global__ __launch_bounds__(512) void bcim_fused(const float* __restrict__ p,
                                                  float* __restrict__ out) {
    __shared__ float shbuf[9216];   // phase1: 2 bufs x 2 slabs x 1540; phase3: 2 x T[128][36]
    __shared__ float invL[192];

    const int tid = threadIdx.x;
    const int b  = blockIdx.x >> 3;
    const int r0 = (blockIdx.x & 7) << 2;
    const float* __restrict__ pb = p + (size_t)b * 131072;

    // ---- loader slots (r17-verified): slot0 = tid (all), slot1 = 512+tid (tid<256) ----
    const int s0wq = tid & 7, s0c = (tid >> 3) & 7, s0r = (tid >> 6) % 6, s0s = tid / 384;
    const int i1   = 512 + tid;
    const int s1wq = i1 & 7,  s1c = (i1 >> 3) & 7,  s1r = (i1 >> 6) % 6;
    const int g0row = r0 - 1 + s0r;
    const int g1row = r0 - 1 + s1r;
    const bool ok0 = ((unsigned)g0row < 32u);
    const bool ok1 = (tid < 256) && ((unsigned)g1row < 32u);
    int w0Off[4], w1Off[4];
    {
        const int ch0 = s0c >> 2, ci0 = s0c & 3;
        const int ch1 = s1c >> 2, ci1 = s1c & 3;
        #pragma unroll
        for (int j = 0; j < 4; ++j) {
            const int u0 = ((s0wq << 3) + (j << 1) + ch0) ^ s0wq;
            const int u1 = ((s1wq << 3) + (j << 1) + ch1) ^ s1wq;
            w0Off[j] = s0s * SLAB_CG + s0r * 256 + u0 * 4 + ci0;
            w1Off[j] = SLAB_CG + s1r * 256 + u1 * 4 + ci1;
        }
    }
    const int gB0 = (s0s * 64 + s0c) * 1024 + g0row * 32 + s0wq * 4;
    const int gB1 = (64 + s1c) * 1024 + g1row * 32 + s1wq * 4;

    // ---- stencil mapping (r17-verified) ----
    const int chalf = tid & 1;
    const int cgrp  = (tid >> 1) & 1;
    const int pos   = tid >> 2;          // 0..127
    const int h     = pos >> 5;          // wave-uniform
    const int w     = pos & 31;
    const int wm    = (w > 0) ? w - 1 : 0;
    const int wp    = (w < 31) ? w + 1 : 31;
    const int uc    = (w  * 2 + chalf) ^ (w  >> 2);
    const int um    = (wm * 2 + chalf) ^ (wm >> 2);
    const int up    = (wp * 2 + chalf) ^ (wp >> 2);
    const int cgOff = cgrp * SLAB_CG;

    #define WRITE(B) {                                                              \
        shbuf[(B) + w0Off[0]] = st0.x; shbuf[(B) + w0Off[1]] = st0.y;               \
        shbuf[(B) + w0Off[2]] = st0.z; shbuf[(B) + w0Off[3]] = st0.w;               \
        if (tid < 256) {                                                            \
            shbuf[(B) + w1Off[0]] = st1.x; shbuf[(B) + w1Off[1]] = st1.y;           \
            shbuf[(B) + w1Off[2]] = st1.z; shbuf[(B) + w1Off[3]] = st1.w;           \
        } }

    float4 st0 = make_float4(0.f, 0.f, 0.f, 0.f), st1 = st0;
    if (ok0) st0 = *(const float4*)(pb + gB0);          // chunk 0
    if (ok1) st1 = *(const float4*)(pb + gB1);
    WRITE(0)                                            // chunk 0 -> buf 0
    if (ok0) st0 = *(const float4*)(pb + 8192 + gB0);   // chunk 1 staged
    if (ok1) st1 = *(const float4*)(pb + 8192 + gB1);
    __syncthreads();

    float s0=0.f,s1=0.f,s2=0.f,s3=0.f,s4=0.f,s5=0.f,s6=0.f,s7=0.f,s8=0.f,hn=0.f;
    __half2 kA[8], kB[8];

    #pragma unroll
    for (int stp = 0; stp < 8; ++stp) {
        if (stp < 7) {
            const int nxt = ((stp + 1) & 1) * SLAB_BUF;
            WRITE(nxt)                                  // chunk stp+1 -> other buf
        }
        if (stp < 6) {                                  // issue chunk stp+2 loads
            if (ok0) st0 = *(const float4*)(pb + (stp + 2) * 8192 + gB0);
            if (ok1) st1 = *(const float4*)(pb + (stp + 2) * 8192 + gB1);
        }
        {
            const float4* sp = (const float4*)(shbuf + (stp & 1) * SLAB_BUF + cgOff);
            const float4 ctr = sp[(h + 1) * 64 + uc];
            kA[stp] = __floats2half2_rn(ctr.x, ctr.y);
            kB[stp] = __floats2half2_rn(ctr.z, ctr.w);
            float4 n0 = sp[h * 64 + um];
            float4 n1 = sp[h * 64 + uc];
            float4 n2 = sp[h * 64 + up];
            s0 = dot4acc(ctr, n0, s0);
            s1 = dot4acc(ctr, n1, s1);
            s2 = dot4acc(ctr, n2, s2);
            if (h == 0) hn = dot4acc(n1, n1, hn);
            n0 = sp[(h + 2) * 64 + um];
            n1 = sp[(h + 2) * 64 + uc];
            n2 = sp[(h + 2) * 64 + up];
            s6 = dot4acc(ctr, n0, s6);
            s7 = dot4acc(ctr, n1, s7);
            s8 = dot4acc(ctr, n2, s8);
            if (h == 3) hn = dot4acc(n1, n1, hn);
            n0 = sp[(h + 1) * 64 + um];
            n2 = sp[(h + 1) * 64 + up];
            s3 = dot4acc(ctr, n0, s3);
            s4 = dot4acc(ctr, ctr, s4);
            s5 = dot4acc(ctr, n2, s5);
        }
        __syncthreads();
    }
    #undef WRITE

    // reduce over chalf (xor 1) then cgroup (xor 2): all 4 lanes get full sums
    s0 += __shfl_xor(s0, 1); s1 += __shfl_xor(s1, 1); s2 += __shfl_xor(s2, 1);
    s3 += __shfl_xor(s3, 1); s4 += __shfl_xor(s4, 1); s5 += __shfl_xor(s5, 1);
    s6 += __shfl_xor(s6, 1); s7 += __shfl_xor(s7, 1); s8 += __shfl_xor(s8, 1);
    hn += __shfl_xor(hn, 1);
    s0 += __shfl_xor(s0, 2); s1 += __shfl_xor(s1, 2); s2 += __shfl_xor(s2, 2);
    s3 += __shfl_xor(s3, 2); s4 += __shfl_xor(s4, 2); s5 += __shfl_xor(s5, 2);
    s6 += __shfl_xor(s6, 2); s7 += __shfl_xor(s7, 2); s8 += __shfl_xor(s8, 2);
    hn += __shfl_xor(hn, 2);

    if ((tid & 3) == 0) {
        invL[(h + 1) * 32 + w] = (s4 > 0.f) ? (1.0f / sqrtf(s4)) : 0.f;
        if (h == 0) invL[w]       = (hn > 0.f) ? (1.0f / sqrtf(hn)) : 0.f;
        if (h == 3) invL[160 + w] = (hn > 0.f) ? (1.0f / sqrtf(hn)) : 0.f;
    }
    __syncthreads();

    float simreg;
    {
        const float mL = (w > 0)  ? 1.f : 0.f;
        const float mR = (w < 31) ? 1.f : 0.f;
        const float* iT = invL + h * 32;
        const float* iM = iT + 32;
        const float* iB = iM + 32;
        float acc;
        acc = s0 * (iT[wm] * mL);
        acc = fmaf(s1, iT[w],       acc);
        acc = fmaf(s2, iT[wp] * mR, acc);
        acc = fmaf(s3, iM[wm] * mL, acc);
        acc = fmaf(s4, iM[w],       acc);
        acc = fmaf(s5, iM[wp] * mR, acc);
        acc = fmaf(s6, iB[wm] * mL, acc);
        acc = fmaf(s7, iB[w],       acc);
        acc = fmaf(s8, iB[wp] * mR, acc);
        simreg = acc * iM[w] * (1.0f / 9.0f);
    }
    __syncthreads();   // all waves done with slabs before T overwrite

    // ---- phase 3: double-buffered aligned exchange tile (r14 layout) ----
    #pragma unroll
    for (int cb = 0; cb < 4; ++cb) {
        float* T = shbuf + (cb & 1) * T_STRIDE;
        if (cgrp == (cb >> 1)) {
            #pragma unroll
            for (int m = 0; m < 4; ++m) {
                const int ki = (cb & 1) * 4 + m;
                const float2 lo = __half22float2(kA[ki]);
                const float2 hi = __half22float2(kB[ki]);
                float4 kk = make_float4(lo.x, lo.y, hi.x, hi.y);
                kk.x *= simreg; kk.y *= simreg; kk.z *= simreg; kk.w *= simreg;
                const int qbase = pos * 36 + m * 4 + chalf * 2;   // even -> aligned
                *(float2*)&T[qbase]      = make_float2(kk.x, kk.z);   // t = 0
                *(float2*)&T[qbase + 16] = make_float2(kk.y, kk.w);   // t = 1
            }
        }
        __syncthreads();
        #pragma unroll
        for (int stp2 = 0; stp2 < 2; ++stp2) {
            const int flat = stp2 * 512 + tid;
            const int qf = flat & 3;
            const int t  = (flat >> 2) & 1;
            const int pp = flat >> 3;
            const int hh = pp >> 5;
            const int ww = pp & 31;
            const float4 o = *(const float4*)&T[pp * 36 + t * 16 + qf * 4];
            *(float4*)(out + (size_t)b * 131072 + (size_t)t * 65536 +
                       (size_t)(r0 + hh) * 2048 + ww * 64 + cb * 16 + qf * 4) = o;
        }
        // no trailing barrier: next cb writes the OTHER T buffer; writes to this
        // one resume only after the next cb's barrier, when these reads are done.
    }
}

extern "C" void kernel_launch(void* const* d_in, const int* in_sizes, int n_in,
                              void* d_out, int out_size, void* d_ws, size_t ws_size,
                              hipStream_t stream) {
    const float* p = (const float*)d_in[0];
    float* out = (float*)d_out;
    bcim_fused<<<dim3(2048), dim3(512), 0, stream>>>(p, out);
    (void)in_sizes; (void)n_in; (void)out_size; (void)d_ws; (void)ws_size;
}

// Round 19
// 60.612 us; speedup vs baseline: 1.0141x; 1.0141x over previous
//
#include <hip/hip_runtime.h>
#include <hip/hip_fp16.h>

// r17 exact (59.7 us, spill-free: WRITE 135 MB, VGPR 52) + ONE change:
// 2-deep A/B prefetch rotation (r14's STEP pattern) instead of 1-deep.
// r17's 1-deep issues chunk k+1's loads after the barrier and needs them
// before the very next WRITE -> HBM/L3 latency only covered by one stencil.
// 2-deep gives each load two stencil-compute windows to land.
//  512 thr, 4 lanes/pos (chalf = tid&1, cgrp = (tid>>1)&1, pos = tid>>2);
//  8 chunks of 8 ch per cgroup; f16 keep; shfl_xor(1)+(2) reduce;
//  stride-36 aligned exchange tile for the output transpose.

__device__ __forceinline__ float dot4acc(float4 a, float4 b, float acc) {
    acc = fmaf(a.x, b.x, acc);
    acc = fmaf(a.y, b.y, acc);
    acc = fmaf(a.z, b.z, acc);
    acc = fmaf(a.w, b.w, acc);
    return acc;
}

__global__ __launch_bounds__(512) void bcim_fused(const float* __restrict__ p,
                                                  float* __restrict__ out) {
    __shared__ float shbuf[4608];   // phase1: 2 slabs x 1536; phase3: T[128][36]
    __shared__ float invL[192];

    const int tid = threadIdx.x;
    const int b  = blockIdx.x >> 3;
    const int r0 = (blockIdx.x & 7) << 2;
    const float* __restrict__ pb = p + (size_t)b * 131072;
    float* slab = shbuf;

    // ---- loader slots (r17-verified): slot0 = tid (all), slot1 = 512+tid (tid<256) ----
    const int s0wq = tid & 7, s0c = (tid >> 3) & 7, s0r = (tid >> 6) % 6, s0s = tid / 384;
    const int i1   = 512 + tid;
    const int s1wq = i1 & 7,  s1c = (i1 >> 3) & 7,  s1r = (i1 >> 6) % 6;
    const int g0row = r0 - 1 + s0r;
    const int g1row = r0 - 1 + s1r;
    const bool ok0 = ((unsigned)g0row < 32u);
    const bool ok1 = (tid < 256) && ((unsigned)g1row < 32u);
    int w0Off[4], w1Off[4];
    {
        const int ch0 = s0c >> 2, ci0 = s0c & 3;
        const int ch1 = s1c >> 2, ci1 = s1c & 3;
        #pragma unroll
        for (int j = 0; j < 4; ++j) {
            const int u0 = ((s0wq << 3) + (j << 1) + ch0) ^ s0wq;
            const int u1 = ((s1wq << 3) + (j << 1) + ch1) ^ s1wq;
            w0Off[j] = s0s * 1536 + s0r * 256 + u0 * 4 + ci0;
            w1Off[j] = 1536 + s1r * 256 + u1 * 4 + ci1;
        }
    }
    const int gB0 = (s0s * 64 + s0c) * 1024 + g0row * 32 + s0wq * 4;
    const int gB1 = (64 + s1c) * 1024 + g1row * 32 + s1wq * 4;

    // ---- stencil mapping (r17-verified) ----
    const int chalf = tid & 1;
    const int cgrp  = (tid >> 1) & 1;
    const int pos   = tid >> 2;          // 0..127
    const int h     = pos >> 5;          // wave-uniform
    const int w     = pos & 31;
    const int wm    = (w > 0) ? w - 1 : 0;
    const int wp    = (w < 31) ? w + 1 : 31;
    const int uc    = (w  * 2 + chalf) ^ (w  >> 2);
    const int um    = (wm * 2 + chalf) ^ (wm >> 2);
    const int up    = (wp * 2 + chalf) ^ (wp >> 2);
    const float4* spC = (const float4*)(slab + cgrp * 1536);

    const float4 z4 = make_float4(0.f, 0.f, 0.f, 0.f);
    float4 A0 = z4, A1 = z4, B0 = z4, B1 = z4;
    if (ok0) A0 = *(const float4*)(pb + gB0);            // chunk 0
    if (ok1) A1 = *(const float4*)(pb + gB1);
    if (ok0) B0 = *(const float4*)(pb + 8192 + gB0);     // chunk 1
    if (ok1) B1 = *(const float4*)(pb + 8192 + gB1);

    float s0=0.f,s1=0.f,s2=0.f,s3=0.f,s4=0.f,s5=0.f,s6=0.f,s7=0.f,s8=0.f,hn=0.f;
    __half2 kA[8], kB[8];

    #define STEP(R0, R1, NEXTC, CUR) {                                              \
        slab[w0Off[0]] = R0.x; slab[w0Off[1]] = R0.y;                               \
        slab[w0Off[2]] = R0.z; slab[w0Off[3]] = R0.w;                               \
        if (tid < 256) {                                                            \
            slab[w1Off[0]] = R1.x; slab[w1Off[1]] = R1.y;                           \
            slab[w1Off[2]] = R1.z; slab[w1Off[3]] = R1.w;                           \
        }                                                                           \
        __syncthreads();                                                            \
        if ((NEXTC) < 8) {                                                          \
            if (ok0) R0 = *(const float4*)(pb + (NEXTC) * 8192 + gB0);              \
            if (ok1) R1 = *(const float4*)(pb + (NEXTC) * 8192 + gB1);              \
        }                                                                           \
        {                                                                           \
            const float4 ctr = spC[(h + 1) * 64 + uc];                              \
            kA[CUR] = __floats2half2_rn(ctr.x, ctr.y);                              \
            kB[CUR] = __floats2half2_rn(ctr.z, ctr.w);                              \
            float4 n0 = spC[h * 64 + um];                                           \
            float4 n1 = spC[h * 64 + uc];                                           \
            float4 n2 = spC[h * 64 + up];                                           \
            s0 = dot4acc(ctr, n0, s0);                                              \
            s1 = dot4acc(ctr, n1, s1);                                              \
            s2 = dot4acc(ctr, n2, s2);                                              \
            if (h == 0) hn = dot4acc(n1, n1, hn);                                   \
            n0 = spC[(h + 2) * 64 + um];                                            \
            n1 = spC[(h + 2) * 64 + uc];                                            \
            n2 = spC[(h + 2) * 64 + up];                                            \
            s6 = dot4acc(ctr, n0, s6);                                              \
            s7 = dot4acc(ctr, n1, s7);                                              \
            s8 = dot4acc(ctr, n2, s8);                                              \
            if (h == 3) hn = dot4acc(n1, n1, hn);                                   \
            n0 = spC[(h + 1) * 64 + um];                                            \
            n2 = spC[(h + 1) * 64 + up];                                            \
            s3 = dot4acc(ctr, n0, s3);                                              \
            s4 = dot4acc(ctr, ctr, s4);                                             \
            s5 = dot4acc(ctr, n2, s5);                                              \
        }                                                                           \
        __syncthreads(); }

    STEP(A0, A1, 2, 0)  STEP(B0, B1, 3, 1)
    STEP(A0, A1, 4, 2)  STEP(B0, B1, 5, 3)
    STEP(A0, A1, 6, 4)  STEP(B0, B1, 7, 5)
    STEP(A0, A1, 8, 6)  STEP(B0, B1, 9, 7)
    #undef STEP

    // reduce over chalf (xor 1) then cgroup (xor 2): all 4 lanes get full sums
    s0 += __shfl_xor(s0, 1); s1 += __shfl_xor(s1, 1); s2 += __shfl_xor(s2, 1);
    s3 += __shfl_xor(s3, 1); s4 += __shfl_xor(s4, 1); s5 += __shfl_xor(s5, 1);
    s6 += __shfl_xor(s6, 1); s7 += __shfl_xor(s7, 1); s8 += __shfl_xor(s8, 1);
    hn += __shfl_xor(hn, 1);
    s0 += __shfl_xor(s0, 2); s1 += __shfl_xor(s1, 2); s2 += __shfl_xor(s2, 2);
    s3 += __shfl_xor(s3, 2); s4 += __shfl_xor(s4, 2); s5 += __shfl_xor(s5, 2);
    s6 += __shfl_xor(s6, 2); s7 += __shfl_xor(s7, 2); s8 += __shfl_xor(s8, 2);
    hn += __shfl_xor(hn, 2);

    if ((tid & 3) == 0) {
        invL[(h + 1) * 32 + w] = (s4 > 0.f) ? (1.0f / sqrtf(s4)) : 0.f;
        if (h == 0) invL[w]       = (hn > 0.f) ? (1.0f / sqrtf(hn)) : 0.f;
        if (h == 3) invL[160 + w] = (hn > 0.f) ? (1.0f / sqrtf(hn)) : 0.f;
    }
    __syncthreads();

    float simreg;
    {
        const float mL = (w > 0)  ? 1.f : 0.f;
        const float mR = (w < 31) ? 1.f : 0.f;
        const float* iT = invL + h * 32;
        const float* iM = iT + 32;
        const float* iB = iM + 32;
        float acc;
        acc = s0 * (iT[wm] * mL);
        acc = fmaf(s1, iT[w],       acc);
        acc = fmaf(s2, iT[wp] * mR, acc);
        acc = fmaf(s3, iM[wm] * mL, acc);
        acc = fmaf(s4, iM[w],       acc);
        acc = fmaf(s5, iM[wp] * mR, acc);
        acc = fmaf(s6, iB[wm] * mL, acc);
        acc = fmaf(s7, iB[w],       acc);
        acc = fmaf(s8, iB[wp] * mR, acc);
        simreg = acc * iM[w] * (1.0f / 9.0f);
    }
    __syncthreads();   // all waves done with slabs before T overwrite

    // ---- phase 3: aligned exchange tile T[128 pos][36] (r14/r17-verified) ----
    float* T = shbuf;
    #pragma unroll
    for (int cb = 0; cb < 4; ++cb) {
        if (cgrp == (cb >> 1)) {
            #pragma unroll
            for (int m = 0; m < 4; ++m) {
                const int ki = (cb & 1) * 4 + m;
                const float2 lo = __half22float2(kA[ki]);
                const float2 hi = __half22float2(kB[ki]);
                float4 kk = make_float4(lo.x, lo.y, hi.x, hi.y);
                kk.x *= simreg; kk.y *= simreg; kk.z *= simreg; kk.w *= simreg;
                const int qbase = pos * 36 + m * 4 + chalf * 2;   // even -> aligned
                *(float2*)&T[qbase]      = make_float2(kk.x, kk.z);   // t = 0
                *(float2*)&T[qbase + 16] = make_float2(kk.y, kk.w);   // t = 1
            }
        }
        __syncthreads();
        #pragma unroll
        for (int stp2 = 0; stp2 < 2; ++stp2) {
            const int flat = stp2 * 512 + tid;
            const int qf = flat & 3;
            const int t  = (flat >> 2) & 1;
            const int pp = flat >> 3;
            const int hh = pp >> 5;
            const int ww = pp & 31;
            const float4 o = *(const float4*)&T[pp * 36 + t * 16 + qf * 4];
            *(float4*)(out + (size_t)b * 131072 + (size_t)t * 65536 +
                       (size_t)(r0 + hh) * 2048 + ww * 64 + cb * 16 + qf * 4) = o;
        }
        __syncthreads();
    }
}

extern "C" void kernel_launch(void* const* d_in, const int* in_sizes, int n_in,
                              void* d_out, int out_size, void* d_ws, size_t ws_size,
                              hipStream_t stream) {
    const float* p = (const float*)d_in[0];
    float* out = (float*)d_out;
    bcim_fused<<<dim3(2048), dim3(512), 0, stream>>>(p, out);
    (void)in_sizes; (void)n_in; (void)out_size; (void)d_ws; (void)ws_size;
}

// Round 20
// 59.082 us; speedup vs baseline: 1.0403x; 1.0259x over previous
//
#include <hip/hip_runtime.h>
#include <hip/hip_fp16.h>

// r17 exact (59.7 us best, spill-free: WRITE 135 MB, VGPR 52) + ONE change:
// XCD-locality block swizzle. Default dispatch round-robins consecutive blocks
// across the 8 XCDs, so the 8 strips of one image run on 8 different XCDs and
// every load is an L3 hit (~450 cy). Remap so all 8 strips of an image land on
// ONE XCD (d%8 selects XCD under round-robin dispatch):
//   b = (d&7)*32 + (d>>3)&31,  strip = d>>8   (bijective for 2048 blocks)
// -> each image's reads (incl. 1.5x halo overlap) are L2-resident (~200 cy).
// Attacks the latency wall that prefetch depth (r19 null) could not.

__device__ __forceinline__ float dot4acc(float4 a, float4 b, float acc) {
    acc = fmaf(a.x, b.x, acc);
    acc = fmaf(a.y, b.y, acc);
    acc = fmaf(a.z, b.z, acc);
    acc = fmaf(a.w, b.w, acc);
    return acc;
}

__global__ __launch_bounds__(512) void bcim_fused(const float* __restrict__ p,
                                                  float* __restrict__ out) {
    __shared__ float shbuf[4608];   // phase1: 2 slabs x 1536; phase3: T[128][36]
    __shared__ float invL[192];

    const int tid = threadIdx.x;
    const int d  = blockIdx.x;
    const int b  = (d & 7) * 32 + ((d >> 3) & 31);   // image -> fixed XCD (d%8)
    const int r0 = (d >> 8) << 2;                    // strip
    const float* __restrict__ pb = p + (size_t)b * 131072;
    float* slab = shbuf;

    // ---- loader slots (r17-verified): slot0 = tid (all), slot1 = 512+tid (tid<256) ----
    const int s0wq = tid & 7, s0c = (tid >> 3) & 7, s0r = (tid >> 6) % 6, s0s = tid / 384;
    const int i1   = 512 + tid;
    const int s1wq = i1 & 7,  s1c = (i1 >> 3) & 7,  s1r = (i1 >> 6) % 6;
    const int g0row = r0 - 1 + s0r;
    const int g1row = r0 - 1 + s1r;
    const bool ok0 = ((unsigned)g0row < 32u);
    const bool ok1 = (tid < 256) && ((unsigned)g1row < 32u);
    int w0Off[4], w1Off[4];
    {
        const int ch0 = s0c >> 2, ci0 = s0c & 3;
        const int ch1 = s1c >> 2, ci1 = s1c & 3;
        #pragma unroll
        for (int j = 0; j < 4; ++j) {
            const int u0 = ((s0wq << 3) + (j << 1) + ch0) ^ s0wq;
            const int u1 = ((s1wq << 3) + (j << 1) + ch1) ^ s1wq;
            w0Off[j] = s0s * 1536 + s0r * 256 + u0 * 4 + ci0;
            w1Off[j] = 1536 + s1r * 256 + u1 * 4 + ci1;
        }
    }
    const int gB0 = (s0s * 64 + s0c) * 1024 + g0row * 32 + s0wq * 4;
    const int gB1 = (64 + s1c) * 1024 + g1row * 32 + s1wq * 4;

    // ---- stencil mapping (r17-verified) ----
    const int chalf = tid & 1;
    const int cgrp  = (tid >> 1) & 1;
    const int pos   = tid >> 2;          // 0..127
    const int h     = pos >> 5;          // wave-uniform
    const int w     = pos & 31;
    const int wm    = (w > 0) ? w - 1 : 0;
    const int wp    = (w < 31) ? w + 1 : 31;
    const int uc    = (w  * 2 + chalf) ^ (w  >> 2);
    const int um    = (wm * 2 + chalf) ^ (wm >> 2);
    const int up    = (wp * 2 + chalf) ^ (wp >> 2);
    const float4* spC = (const float4*)(slab + cgrp * 1536);

    float4 st0 = make_float4(0.f, 0.f, 0.f, 0.f), st1 = st0;
    if (ok0) st0 = *(const float4*)(pb + gB0);
    if (ok1) st1 = *(const float4*)(pb + gB1);

    float s0=0.f,s1=0.f,s2=0.f,s3=0.f,s4=0.f,s5=0.f,s6=0.f,s7=0.f,s8=0.f,hn=0.f;
    __half2 kA[8], kB[8];

    #pragma unroll
    for (int stp = 0; stp < 8; ++stp) {
        slab[w0Off[0]] = st0.x; slab[w0Off[1]] = st0.y;
        slab[w0Off[2]] = st0.z; slab[w0Off[3]] = st0.w;
        if (tid < 256) {
            slab[w1Off[0]] = st1.x; slab[w1Off[1]] = st1.y;
            slab[w1Off[2]] = st1.z; slab[w1Off[3]] = st1.w;
        }
        __syncthreads();
        if (stp < 7) {      // issue next step's loads; latency hides under stencil
            if (ok0) st0 = *(const float4*)(pb + (stp + 1) * 8192 + gB0);
            if (ok1) st1 = *(const float4*)(pb + (stp + 1) * 8192 + gB1);
        }
        {
            const float4 ctr = spC[(h + 1) * 64 + uc];
            kA[stp] = __floats2half2_rn(ctr.x, ctr.y);
            kB[stp] = __floats2half2_rn(ctr.z, ctr.w);
            float4 n0 = spC[h * 64 + um];
            float4 n1 = spC[h * 64 + uc];
            float4 n2 = spC[h * 64 + up];
            s0 = dot4acc(ctr, n0, s0);
            s1 = dot4acc(ctr, n1, s1);
            s2 = dot4acc(ctr, n2, s2);
            if (h == 0) hn = dot4acc(n1, n1, hn);
            n0 = spC[(h + 2) * 64 + um];
            n1 = spC[(h + 2) * 64 + uc];
            n2 = spC[(h + 2) * 64 + up];
            s6 = dot4acc(ctr, n0, s6);
            s7 = dot4acc(ctr, n1, s7);
            s8 = dot4acc(ctr, n2, s8);
            if (h == 3) hn = dot4acc(n1, n1, hn);
            n0 = spC[(h + 1) * 64 + um];
            n2 = spC[(h + 1) * 64 + up];
            s3 = dot4acc(ctr, n0, s3);
            s4 = dot4acc(ctr, ctr, s4);
            s5 = dot4acc(ctr, n2, s5);
        }
        __syncthreads();
    }

    // reduce over chalf (xor 1) then cgroup (xor 2): all 4 lanes get full sums
    s0 += __shfl_xor(s0, 1); s1 += __shfl_xor(s1, 1); s2 += __shfl_xor(s2, 1);
    s3 += __shfl_xor(s3, 1); s4 += __shfl_xor(s4, 1); s5 += __shfl_xor(s5, 1);
    s6 += __shfl_xor(s6, 1); s7 += __shfl_xor(s7, 1); s8 += __shfl_xor(s8, 1);
    hn += __shfl_xor(hn, 1);
    s0 += __shfl_xor(s0, 2); s1 += __shfl_xor(s1, 2); s2 += __shfl_xor(s2, 2);
    s3 += __shfl_xor(s3, 2); s4 += __shfl_xor(s4, 2); s5 += __shfl_xor(s5, 2);
    s6 += __shfl_xor(s6, 2); s7 += __shfl_xor(s7, 2); s8 += __shfl_xor(s8, 2);
    hn += __shfl_xor(hn, 2);

    if ((tid & 3) == 0) {
        invL[(h + 1) * 32 + w] = (s4 > 0.f) ? (1.0f / sqrtf(s4)) : 0.f;
        if (h == 0) invL[w]       = (hn > 0.f) ? (1.0f / sqrtf(hn)) : 0.f;
        if (h == 3) invL[160 + w] = (hn > 0.f) ? (1.0f / sqrtf(hn)) : 0.f;
    }
    __syncthreads();

    float simreg;
    {
        const float mL = (w > 0)  ? 1.f : 0.f;
        const float mR = (w < 31) ? 1.f : 0.f;
        const float* iT = invL + h * 32;
        const float* iM = iT + 32;
        const float* iB = iM + 32;
        float acc;
        acc = s0 * (iT[wm] * mL);
        acc = fmaf(s1, iT[w],       acc);
        acc = fmaf(s2, iT[wp] * mR, acc);
        acc = fmaf(s3, iM[wm] * mL, acc);
        acc = fmaf(s4, iM[w],       acc);
        acc = fmaf(s5, iM[wp] * mR, acc);
        acc = fmaf(s6, iB[wm] * mL, acc);
        acc = fmaf(s7, iB[w],       acc);
        acc = fmaf(s8, iB[wp] * mR, acc);
        simreg = acc * iM[w] * (1.0f / 9.0f);
    }
    __syncthreads();   // all waves done with slabs before T overwrite

    // ---- phase 3: aligned exchange tile T[128 pos][36] (r14/r17-verified) ----
    float* T = shbuf;
    #pragma unroll
    for (int cb = 0; cb < 4; ++cb) {
        if (cgrp == (cb >> 1)) {
            #pragma unroll
            for (int m = 0; m < 4; ++m) {
                const int ki = (cb & 1) * 4 + m;
                const float2 lo = __half22float2(kA[ki]);
                const float2 hi = __half22float2(kB[ki]);
                float4 kk = make_float4(lo.x, lo.y, hi.x, hi.y);
                kk.x *= simreg; kk.y *= simreg; kk.z *= simreg; kk.w *= simreg;
                const int qbase = pos * 36 + m * 4 + chalf * 2;   // even -> aligned
                *(float2*)&T[qbase]      = make_float2(kk.x, kk.z);   // t = 0
                *(float2*)&T[qbase + 16] = make_float2(kk.y, kk.w);   // t = 1
            }
        }
        __syncthreads();
        #pragma unroll
        for (int stp2 = 0; stp2 < 2; ++stp2) {
            const int flat = stp2 * 512 + tid;
            const int qf = flat & 3;
            const int t  = (flat >> 2) & 1;
            const int pp = flat >> 3;
            const int hh = pp >> 5;
            const int ww = pp & 31;
            const float4 o = *(const float4*)&T[pp * 36 + t * 16 + qf * 4];
            *(float4*)(out + (size_t)b * 131072 + (size_t)t * 65536 +
                       (size_t)(r0 + hh) * 2048 + ww * 64 + cb * 16 + qf * 4) = o;
        }
        __syncthreads();
    }
}

extern "C" void kernel_launch(void* const* d_in, const int* in_sizes, int n_in,
                              void* d_out, int out_size, void* d_ws, size_t ws_size,
                              hipStream_t stream) {
    const float* p = (const float*)d_in[0];
    float* out = (float*)d_out;
    bcim_fused<<<dim3(2048), dim3(512), 0, stream>>>(p, out);
    (void)in_sizes; (void)n_in; (void)out_size; (void)d_ws; (void)ws_size;
}

// Round 21
// 58.288 us; speedup vs baseline: 1.0545x; 1.0136x over previous
//
#include <hip/hip_runtime.h>
#include <hip/hip_fp16.h>

// r20 base (59.1 us best, FETCH 78 MB w/ XCD swizzle) + stencil restructure:
// lanes remapped so a wave spans one full row (w = tid&31, chalf = bit5,
// cgrp = bit6, h = bit7+). The w+-1 neighbor quad is then lane+-1 -> DPP
// wave_shr1/wave_shl1 (pure VALU) replaces 6 of the 9 ds_read_b128 per
// thread per chunk. LDS-pipe arithmetic says phase-1 reads were ~60% of the
// per-CU LDS occupancy that pins the 59 us plateau. Image edge == wave edge;
// the mL/mR-masked inv weights already nullify all shifted-in garbage.
// cgrp reduce (now cross-wave) via one 10-float LDS round-trip per block.

__device__ __forceinline__ float dot4acc(float4 a, float4 b, float acc) {
    acc = fmaf(a.x, b.x, acc);
    acc = fmaf(a.y, b.y, acc);
    acc = fmaf(a.z, b.z, acc);
    acc = fmaf(a.w, b.w, acc);
    return acc;
}

// lane i <- lane i-1 (shfl_up 1) / lane i <- lane i+1 (shfl_down 1), 0 at ends
__device__ __forceinline__ float wshr1(float x) {
    return __int_as_float(__builtin_amdgcn_update_dpp(
        0, __float_as_int(x), 0x138, 0xF, 0xF, true));   // WAVE_SHR1
}
__device__ __forceinline__ float wshl1(float x) {
    return __int_as_float(__builtin_amdgcn_update_dpp(
        0, __float_as_int(x), 0x130, 0xF, 0xF, true));   // WAVE_SHL1
}
__device__ __forceinline__ float4 f4shr(float4 v) {
    return make_float4(wshr1(v.x), wshr1(v.y), wshr1(v.z), wshr1(v.w));
}
__device__ __forceinline__ float4 f4shl(float4 v) {
    return make_float4(wshl1(v.x), wshl1(v.y), wshl1(v.z), wshl1(v.w));
}

__global__ __launch_bounds__(512) void bcim_fused(const float* __restrict__ p,
                                                  float* __restrict__ out) {
    __shared__ float shbuf[4608];   // phase1: 2 slabs x 1536; reduce R[128][12]; phase3: T[128][36]
    __shared__ float invL[192];
    __shared__ float simv[128];

    const int tid = threadIdx.x;
    const int d  = blockIdx.x;
    const int b  = (d & 7) * 32 + ((d >> 3) & 31);   // image -> fixed XCD (r20-verified)
    const int r0 = (d >> 8) << 2;                    // strip
    const float* __restrict__ pb = p + (size_t)b * 131072;
    float* slab = shbuf;

    // ---- loader slots (r17-verified, tid-based, unchanged) ----
    const int s0wq = tid & 7, s0c = (tid >> 3) & 7, s0r = (tid >> 6) % 6, s0s = tid / 384;
    const int i1   = 512 + tid;
    const int s1wq = i1 & 7,  s1c = (i1 >> 3) & 7,  s1r = (i1 >> 6) % 6;
    const int g0row = r0 - 1 + s0r;
    const int g1row = r0 - 1 + s1r;
    const bool ok0 = ((unsigned)g0row < 32u);
    const bool ok1 = (tid < 256) && ((unsigned)g1row < 32u);
    int w0Off[4], w1Off[4];
    {
        const int ch0 = s0c >> 2, ci0 = s0c & 3;
        const int ch1 = s1c >> 2, ci1 = s1c & 3;
        #pragma unroll
        for (int j = 0; j < 4; ++j) {
            const int u0 = ((s0wq << 3) + (j << 1) + ch0) ^ s0wq;
            const int u1 = ((s1wq << 3) + (j << 1) + ch1) ^ s1wq;
            w0Off[j] = s0s * 1536 + s0r * 256 + u0 * 4 + ci0;
            w1Off[j] = 1536 + s1r * 256 + u1 * 4 + ci1;
        }
    }
    const int gB0 = (s0s * 64 + s0c) * 1024 + g0row * 32 + s0wq * 4;
    const int gB1 = (64 + s1c) * 1024 + g1row * 32 + s1wq * 4;

    // ---- NEW stencil mapping: wave = one full row ----
    const int w     = tid & 31;          // lane bits 0-4
    const int chalf = (tid >> 5) & 1;    // lane bit 5
    const int cgrp  = (tid >> 6) & 1;    // wave bit 0
    const int h     = tid >> 7;          // wave bits 1-2 (0..3)
    const int pos   = h * 32 + w;
    const int wm    = (w > 0) ? w - 1 : 0;
    const int wp    = (w < 31) ? w + 1 : 31;
    const int uc    = (w * 2 + chalf) ^ (w >> 2);
    const float4* spC = (const float4*)(slab + cgrp * 1536);

    float4 st0 = make_float4(0.f, 0.f, 0.f, 0.f), st1 = st0;
    if (ok0) st0 = *(const float4*)(pb + gB0);
    if (ok1) st1 = *(const float4*)(pb + gB1);

    float s0=0.f,s1=0.f,s2=0.f,s3=0.f,s4=0.f,s5=0.f,s6=0.f,s7=0.f,s8=0.f,hn=0.f;
    __half2 kA[8], kB[8];

    #pragma unroll
    for (int stp = 0; stp < 8; ++stp) {
        slab[w0Off[0]] = st0.x; slab[w0Off[1]] = st0.y;
        slab[w0Off[2]] = st0.z; slab[w0Off[3]] = st0.w;
        if (tid < 256) {
            slab[w1Off[0]] = st1.x; slab[w1Off[1]] = st1.y;
            slab[w1Off[2]] = st1.z; slab[w1Off[3]] = st1.w;
        }
        __syncthreads();
        if (stp < 7) {
            if (ok0) st0 = *(const float4*)(pb + (stp + 1) * 8192 + gB0);
            if (ok1) st1 = *(const float4*)(pb + (stp + 1) * 8192 + gB1);
        }
        {
            const float4 qt = spC[(h + 0) * 64 + uc];   // only 3 LDS reads
            const float4 qc = spC[(h + 1) * 64 + uc];
            const float4 qb = spC[(h + 2) * 64 + uc];
            kA[stp] = __floats2half2_rn(qc.x, qc.y);
            kB[stp] = __floats2half2_rn(qc.z, qc.w);
            // neighbors via DPP wave shifts (garbage at w=0/31 masked by mL/mR weights)
            s0 = dot4acc(qc, f4shr(qt), s0);
            s1 = dot4acc(qc, qt,        s1);
            s2 = dot4acc(qc, f4shl(qt), s2);
            if (h == 0) hn = dot4acc(qt, qt, hn);
            s3 = dot4acc(qc, f4shr(qc), s3);
            s4 = dot4acc(qc, qc,        s4);
            s5 = dot4acc(qc, f4shl(qc), s5);
            s6 = dot4acc(qc, f4shr(qb), s6);
            s7 = dot4acc(qc, qb,        s7);
            s8 = dot4acc(qc, f4shl(qb), s8);
            if (h == 3) hn = dot4acc(qb, qb, hn);
        }
        __syncthreads();
    }

    // ---- chalf reduce (in-wave, lane^32) ----
    s0 += __shfl_xor(s0, 32); s1 += __shfl_xor(s1, 32); s2 += __shfl_xor(s2, 32);
    s3 += __shfl_xor(s3, 32); s4 += __shfl_xor(s4, 32); s5 += __shfl_xor(s5, 32);
    s6 += __shfl_xor(s6, 32); s7 += __shfl_xor(s7, 32); s8 += __shfl_xor(s8, 32);
    hn += __shfl_xor(hn, 32);

    // ---- cgrp reduce (cross-wave) via R[128][12] overlaying the slab area ----
    float* R = shbuf;
    if (cgrp == 1 && chalf == 0) {
        const int rb = pos * 12;
        R[rb+0]=s0; R[rb+1]=s1; R[rb+2]=s2; R[rb+3]=s3; R[rb+4]=s4;
        R[rb+5]=s5; R[rb+6]=s6; R[rb+7]=s7; R[rb+8]=s8; R[rb+9]=hn;
    }
    __syncthreads();
    if (cgrp == 0) {
        const int rb = pos * 12;
        s0 += R[rb+0]; s1 += R[rb+1]; s2 += R[rb+2]; s3 += R[rb+3]; s4 += R[rb+4];
        s5 += R[rb+5]; s6 += R[rb+6]; s7 += R[rb+7]; s8 += R[rb+8]; hn += R[rb+9];
        if (chalf == 0) {
            invL[(h + 1) * 32 + w] = (s4 > 0.f) ? (1.0f / sqrtf(s4)) : 0.f;
            if (h == 0) invL[w]       = (hn > 0.f) ? (1.0f / sqrtf(hn)) : 0.f;
            if (h == 3) invL[160 + w] = (hn > 0.f) ? (1.0f / sqrtf(hn)) : 0.f;
        }
    }
    __syncthreads();
    if (cgrp == 0 && chalf == 0) {
        const float mL = (w > 0)  ? 1.f : 0.f;
        const float mR = (w < 31) ? 1.f : 0.f;
        const float* iT = invL + h * 32;
        const float* iM = iT + 32;
        const float* iB = iM + 32;
        float acc;
        acc = s0 * (iT[wm] * mL);
        acc = fmaf(s1, iT[w],       acc);
        acc = fmaf(s2, iT[wp] * mR, acc);
        acc = fmaf(s3, iM[wm] * mL, acc);
        acc = fmaf(s4, iM[w],       acc);
        acc = fmaf(s5, iM[wp] * mR, acc);
        acc = fmaf(s6, iB[wm] * mL, acc);
        acc = fmaf(s7, iB[w],       acc);
        acc = fmaf(s8, iB[wp] * mR, acc);
        simv[pos] = acc * iM[w] * (1.0f / 9.0f);
    }
    __syncthreads();
    const float simreg = simv[pos];   // 2-way broadcast, free
    __syncthreads();                  // simv read before T overwrites shbuf? (T is shbuf; simv separate — barrier guards R/slab reuse)

    // ---- phase 3: aligned exchange tile T[128 pos][36] (r14/r17-verified) ----
    float* T = shbuf;
    #pragma unroll
    for (int cb = 0; cb < 4; ++cb) {
        if (cgrp == (cb >> 1)) {
            #pragma unroll
            for (int m = 0; m < 4; ++m) {
                const int ki = (cb & 1) * 4 + m;
                const float2 lo = __half22float2(kA[ki]);
                const float2 hi = __half22float2(kB[ki]);
                float4 kk = make_float4(lo.x, lo.y, hi.x, hi.y);
                kk.x *= simreg; kk.y *= simreg; kk.z *= simreg; kk.w *= simreg;
                const int qbase = pos * 36 + m * 4 + chalf * 2;   // even -> aligned
                *(float2*)&T[qbase]      = make_float2(kk.x, kk.z);   // t = 0
                *(float2*)&T[qbase + 16] = make_float2(kk.y, kk.w);   // t = 1
            }
        }
        __syncthreads();
        #pragma unroll
        for (int stp2 = 0; stp2 < 2; ++stp2) {
            const int flat = stp2 * 512 + tid;
            const int qf = flat & 3;
            const int t  = (flat >> 2) & 1;
            const int pp = flat >> 3;
            const int hh = pp >> 5;
            const int ww = pp & 31;
            const float4 o = *(const float4*)&T[pp * 36 + t * 16 + qf * 4];
            *(float4*)(out + (size_t)b * 131072 + (size_t)t * 65536 +
                       (size_t)(r0 + hh) * 2048 + ww * 64 + cb * 16 + qf * 4) = o;
        }
        __syncthreads();
    }
}

extern "C" void kernel_launch(void* const* d_in, const int* in_sizes, int n_in,
                              void* d_out, int out_size, void* d_ws, size_t ws_size,
                              hipStream_t stream) {
    const float* p = (const float*)d_in[0];
    float* out = (float*)d_out;
    bcim_fused<<<dim3(2048), dim3(512), 0, stream>>>(p, out);
    (void)in_sizes; (void)n_in; (void)out_size; (void)d_ws; (void)ws_size;
}

// Round 22
// 57.122 us; speedup vs baseline: 1.0760x; 1.0204x over previous
//
#include <hip/hip_runtime.h>
#include <hip/hip_fp16.h>

// r21 base (58.3 us best) + phase-3 rework:
//  (a) 2-wide exchange: both cgrp halves write their OWN tile per round
//      (T0 <- cb{0,1} by cgrp0, T1 <- cb{2,3} by cgrp1): 2 rounds, 4 barriers,
//      no idle writers (r21 idled half the threads per cb round).
//  (b) XOR slot swizzle physslot = (2m+chalf)^((w>>2)&7): kills the 8-lane
//      writer bank aliasing of the stride-36 tile (banks 4w%32: lanes w,w+8,
//      w+16,w+24 collided). Reader compensates with a conditional half-swap;
//      reads remain conflict-free (each pp-region spans all 32 banks once).
//  (c) reduce slab stride 12 -> 13 (gcd(13,32)=1, conflict-free).
// All else r21-exact: XCD swizzle, wave-row DPP stencil, f16 keep, 1-deep
// prefetch, shfl chalf-reduce + LDS cgrp-reduce.

__device__ __forceinline__ float dot4acc(float4 a, float4 b, float acc) {
    acc = fmaf(a.x, b.x, acc);
    acc = fmaf(a.y, b.y, acc);
    acc = fmaf(a.z, b.z, acc);
    acc = fmaf(a.w, b.w, acc);
    return acc;
}

__device__ __forceinline__ float wshr1(float x) {
    return __int_as_float(__builtin_amdgcn_update_dpp(
        0, __float_as_int(x), 0x138, 0xF, 0xF, true));   // WAVE_SHR1
}
__device__ __forceinline__ float wshl1(float x) {
    return __int_as_float(__builtin_amdgcn_update_dpp(
        0, __float_as_int(x), 0x130, 0xF, 0xF, true));   // WAVE_SHL1
}
__device__ __forceinline__ float4 f4shr(float4 v) {
    return make_float4(wshr1(v.x), wshr1(v.y), wshr1(v.z), wshr1(v.w));
}
__device__ __forceinline__ float4 f4shl(float4 v) {
    return make_float4(wshl1(v.x), wshl1(v.y), wshl1(v.z), wshl1(v.w));
}

__global__ __launch_bounds__(512) void bcim_fused(const float* __restrict__ p,
                                                  float* __restrict__ out) {
    __shared__ float shbuf[9216];   // phase1: 2 slabs x 1536; R[128][13]; phase3: 2 x T[128][36]
    __shared__ float invL[192];
    __shared__ float simv[128];

    const int tid = threadIdx.x;
    const int d  = blockIdx.x;
    const int b  = (d & 7) * 32 + ((d >> 3) & 31);   // image -> fixed XCD (r20-verified)
    const int r0 = (d >> 8) << 2;                    // strip
    const float* __restrict__ pb = p + (size_t)b * 131072;
    float* slab = shbuf;

    // ---- loader slots (r17-verified) ----
    const int s0wq = tid & 7, s0c = (tid >> 3) & 7, s0r = (tid >> 6) % 6, s0s = tid / 384;
    const int i1   = 512 + tid;
    const int s1wq = i1 & 7,  s1c = (i1 >> 3) & 7,  s1r = (i1 >> 6) % 6;
    const int g0row = r0 - 1 + s0r;
    const int g1row = r0 - 1 + s1r;
    const bool ok0 = ((unsigned)g0row < 32u);
    const bool ok1 = (tid < 256) && ((unsigned)g1row < 32u);
    int w0Off[4], w1Off[4];
    {
        const int ch0 = s0c >> 2, ci0 = s0c & 3;
        const int ch1 = s1c >> 2, ci1 = s1c & 3;
        #pragma unroll
        for (int j = 0; j < 4; ++j) {
            const int u0 = ((s0wq << 3) + (j << 1) + ch0) ^ s0wq;
            const int u1 = ((s1wq << 3) + (j << 1) + ch1) ^ s1wq;
            w0Off[j] = s0s * 1536 + s0r * 256 + u0 * 4 + ci0;
            w1Off[j] = 1536 + s1r * 256 + u1 * 4 + ci1;
        }
    }
    const int gB0 = (s0s * 64 + s0c) * 1024 + g0row * 32 + s0wq * 4;
    const int gB1 = (64 + s1c) * 1024 + g1row * 32 + s1wq * 4;

    // ---- stencil mapping (r21-verified): wave = one full row ----
    const int w     = tid & 31;          // lane bits 0-4
    const int chalf = (tid >> 5) & 1;    // lane bit 5
    const int cgrp  = (tid >> 6) & 1;    // wave bit 0
    const int h     = tid >> 7;          // wave bits 1-2
    const int pos   = h * 32 + w;
    const int wm    = (w > 0) ? w - 1 : 0;
    const int wp    = (w < 31) ? w + 1 : 31;
    const int uc    = (w * 2 + chalf) ^ (w >> 2);
    const float4* spC = (const float4*)(slab + cgrp * 1536);

    float4 st0 = make_float4(0.f, 0.f, 0.f, 0.f), st1 = st0;
    if (ok0) st0 = *(const float4*)(pb + gB0);
    if (ok1) st1 = *(const float4*)(pb + gB1);

    float s0=0.f,s1=0.f,s2=0.f,s3=0.f,s4=0.f,s5=0.f,s6=0.f,s7=0.f,s8=0.f,hn=0.f;
    __half2 kA[8], kB[8];

    #pragma unroll
    for (int stp = 0; stp < 8; ++stp) {
        slab[w0Off[0]] = st0.x; slab[w0Off[1]] = st0.y;
        slab[w0Off[2]] = st0.z; slab[w0Off[3]] = st0.w;
        if (tid < 256) {
            slab[w1Off[0]] = st1.x; slab[w1Off[1]] = st1.y;
            slab[w1Off[2]] = st1.z; slab[w1Off[3]] = st1.w;
        }
        __syncthreads();
        if (stp < 7) {
            if (ok0) st0 = *(const float4*)(pb + (stp + 1) * 8192 + gB0);
            if (ok1) st1 = *(const float4*)(pb + (stp + 1) * 8192 + gB1);
        }
        {
            const float4 qt = spC[(h + 0) * 64 + uc];
            const float4 qc = spC[(h + 1) * 64 + uc];
            const float4 qb = spC[(h + 2) * 64 + uc];
            kA[stp] = __floats2half2_rn(qc.x, qc.y);
            kB[stp] = __floats2half2_rn(qc.z, qc.w);
            s0 = dot4acc(qc, f4shr(qt), s0);
            s1 = dot4acc(qc, qt,        s1);
            s2 = dot4acc(qc, f4shl(qt), s2);
            if (h == 0) hn = dot4acc(qt, qt, hn);
            s3 = dot4acc(qc, f4shr(qc), s3);
            s4 = dot4acc(qc, qc,        s4);
            s5 = dot4acc(qc, f4shl(qc), s5);
            s6 = dot4acc(qc, f4shr(qb), s6);
            s7 = dot4acc(qc, qb,        s7);
            s8 = dot4acc(qc, f4shl(qb), s8);
            if (h == 3) hn = dot4acc(qb, qb, hn);
        }
        __syncthreads();
    }

    // ---- chalf reduce (in-wave, lane^32) ----
    s0 += __shfl_xor(s0, 32); s1 += __shfl_xor(s1, 32); s2 += __shfl_xor(s2, 32);
    s3 += __shfl_xor(s3, 32); s4 += __shfl_xor(s4, 32); s5 += __shfl_xor(s5, 32);
    s6 += __shfl_xor(s6, 32); s7 += __shfl_xor(s7, 32); s8 += __shfl_xor(s8, 32);
    hn += __shfl_xor(hn, 32);

    // ---- cgrp reduce via R[128][13] (stride 13: conflict-free) ----
    float* R = shbuf;
    if (cgrp == 1 && chalf == 0) {
        const int rb = pos * 13;
        R[rb+0]=s0; R[rb+1]=s1; R[rb+2]=s2; R[rb+3]=s3; R[rb+4]=s4;
        R[rb+5]=s5; R[rb+6]=s6; R[rb+7]=s7; R[rb+8]=s8; R[rb+9]=hn;
    }
    __syncthreads();
    if (cgrp == 0) {
        const int rb = pos * 13;
        s0 += R[rb+0]; s1 += R[rb+1]; s2 += R[rb+2]; s3 += R[rb+3]; s4 += R[rb+4];
        s5 += R[rb+5]; s6 += R[rb+6]; s7 += R[rb+7]; s8 += R[rb+8]; hn += R[rb+9];
        if (chalf == 0) {
            invL[(h + 1) * 32 + w] = (s4 > 0.f) ? (1.0f / sqrtf(s4)) : 0.f;
            if (h == 0) invL[w]       = (hn > 0.f) ? (1.0f / sqrtf(hn)) : 0.f;
            if (h == 3) invL[160 + w] = (hn > 0.f) ? (1.0f / sqrtf(hn)) : 0.f;
        }
    }
    __syncthreads();
    if (cgrp == 0 && chalf == 0) {
        const float mL = (w > 0)  ? 1.f : 0.f;
        const float mR = (w < 31) ? 1.f : 0.f;
        const float* iT = invL + h * 32;
        const float* iM = iT + 32;
        const float* iB = iM + 32;
        float acc;
        acc = s0 * (iT[wm] * mL);
        acc = fmaf(s1, iT[w],       acc);
        acc = fmaf(s2, iT[wp] * mR, acc);
        acc = fmaf(s3, iM[wm] * mL, acc);
        acc = fmaf(s4, iM[w],       acc);
        acc = fmaf(s5, iM[wp] * mR, acc);
        acc = fmaf(s6, iB[wm] * mL, acc);
        acc = fmaf(s7, iB[w],       acc);
        acc = fmaf(s8, iB[wp] * mR, acc);
        simv[pos] = acc * iM[w] * (1.0f / 9.0f);
    }
    __syncthreads();
    const float simreg = simv[pos];
    __syncthreads();   // simv/R consumed before tile overwrite

    // ---- phase 3: 2-wide XOR-swizzled exchange tiles ----
    // cgrp g owns output q-block cb = g*2 + cbp; writes tile T_g.
    // f2 slot s = m*2+chalf holds q-local {2s,2s+1}; physical slot = s ^ xsw.
    const int xsw = (w >> 2) & 7;
    #pragma unroll
    for (int cbp = 0; cbp < 2; ++cbp) {
        float* Tg = shbuf + cgrp * 4608;
        #pragma unroll
        for (int m = 0; m < 4; ++m) {
            const int ki = cbp * 4 + m;
            const float2 lo = __half22float2(kA[ki]);
            const float2 hi = __half22float2(kB[ki]);
            float4 kk = make_float4(lo.x, lo.y, hi.x, hi.y);
            kk.x *= simreg; kk.y *= simreg; kk.z *= simreg; kk.w *= simreg;
            const int sp2 = ((m * 2 + chalf) ^ xsw) << 1;
            const int base = pos * 36;
            *(float2*)&Tg[base + sp2]      = make_float2(kk.x, kk.z);   // t = 0
            *(float2*)&Tg[base + 16 + sp2] = make_float2(kk.y, kk.w);   // t = 1
        }
        __syncthreads();
        #pragma unroll
        for (int stp2 = 0; stp2 < 4; ++stp2) {
            const int flat = stp2 * 512 + tid;       // 0..2047
            const int qf = flat & 3;
            const int t  = (flat >> 2) & 1;
            const int pp = (flat >> 3) & 127;
            const int cbsel = flat >> 10;            // tile select
            const int hh = pp >> 5;
            const int ww = pp & 31;
            const int xr = (ww >> 2) & 7;
            const int p0 = (qf << 1) ^ xr;           // physical f2 slot of pair0
            float4 o = *(const float4*)&shbuf[cbsel * 4608 + pp * 36 + t * 16 +
                                              ((p0 & ~1) << 1)];
            if (p0 & 1) o = make_float4(o.z, o.w, o.x, o.y);
            const int cb = cbp + (cbsel << 1);
            *(float4*)(out + (size_t)b * 131072 + (size_t)t * 65536 +
                       (size_t)(r0 + hh) * 2048 + ww * 64 + cb * 16 + qf * 4) = o;
        }
        __syncthreads();
    }
}

extern "C" void kernel_launch(void* const* d_in, const int* in_sizes, int n_in,
                              void* d_out, int out_size, void* d_ws, size_t ws_size,
                              hipStream_t stream) {
    const float* p = (const float*)d_in[0];
    float* out = (float*)d_out;
    bcim_fused<<<dim3(2048), dim3(512), 0, stream>>>(p, out);
    (void)in_sizes; (void)n_in; (void)out_size; (void)d_ws; (void)ws_size;
}